// Round 9
// baseline (127.200 us; speedup 1.0000x reference)
//
#include <hip/hip_runtime.h>
#include <hip/hip_bf16.h>

#define B_ 512
#define C_ 22
#define TIN 1001
#define K_ 40
#define KS_ 25
#define TO 976
#define P_ 100
#define NW 9
#define NOUT 4
#define FCIN 360

#define XTROWS 1088               /* padded rows of XTg (0..999 data, rest 0) */
#define SROWS 320                 /* rows staged per conv block */
#define STG_BYTES (SROWS * 64)    /* 20480 */
#define RED_OFF STG_BYTES
#define RED_BYTES (K_ * 4 * 2 * 4) /* 1280 */
#define LDS_TOTAL (RED_OFF + RED_BYTES) /* 21760 */
#define NBLKQ 2048
#define NPAD 48
#define WB_ELEM_S (KS_ * NPAD * 32) /* 38400 */

typedef __attribute__((ext_vector_type(8))) short bf16x8;
typedef __attribute__((ext_vector_type(4))) float f32x4;
typedef __attribute__((ext_vector_type(4))) int i32x4;

__device__ __forceinline__ float waveReduceSum(float v) {
#pragma unroll
  for (int m = 32; m >= 1; m >>= 1) v += __shfl_xor(v, m, 64);
  return v;
}

__device__ __forceinline__ unsigned short f2bf(float f) {
  __hip_bfloat16 h = __float2bfloat16(f);
  return *reinterpret_cast<unsigned short*>(&h);
}

__device__ __forceinline__ void gll16(const void* g, void* l) {
  __builtin_amdgcn_global_load_lds(
      (const __attribute__((address_space(1))) unsigned int*)g,
      (__attribute__((address_space(3))) unsigned int*)l, 16, 0, 0);
}

// W[s][n][c][j] fp32 -> WBg[s][j][n(48)][c(32)] bf16, zero-padded.
__global__ __launch_bounds__(192) void wconv_kernel(const float* __restrict__ W,
                                                    unsigned short* __restrict__ WBg) {
  const int s = blockIdx.x / KS_;
  const int j = blockIdx.x % KS_;
  const int n = threadIdx.x >> 2;
  const int q = threadIdx.x & 3;
  union {
    unsigned short u[8];
    i32x4 v;
  } pk;
#pragma unroll
  for (int e = 0; e < 8; ++e) {
    const int c = q * 8 + e;
    float v = 0.f;
    if (n < K_ && c < C_) v = W[(((size_t)s * K_ + n) * C_ + c) * KS_ + j];
    pk.u[e] = f2bf(v);
  }
  *(i32x4*)(WBg + ((size_t)(s * KS_ + j) * NPAD + n) * 32 + q * 8) = pk.v;
}

// x[b][c][t] fp32 -> XTg[b][t(1088)][c(32)] bf16, chunk-XOR swizzle baked:
// physical chunk q at row t holds logical chunk q ^ ((t>>1)&3). Rows >= 1000
// are zeros. Byte layout identical to the conv kernel's LDS image.
__global__ __launch_bounds__(256) void xpose_kernel(const float* __restrict__ x,
                                                    unsigned short* __restrict__ XTg) {
  const int b = blockIdx.x;
  const float* xb = x + (size_t)b * (C_ * TIN);
  unsigned short* xt = XTg + (size_t)b * XTROWS * 32;
#pragma unroll 1
  for (int r = 0; r < 17; ++r) {  // 4*1088 = 4352 = 17*256 tasks
    const int task = threadIdx.x + r * 256;
    const int q = task / XTROWS;       // physical 16B chunk (coalesced reads)
    const int tr = task - q * XTROWS;  // row
    const int lq = q ^ ((tr >> 1) & 3);
    union {
      unsigned short u[8];
      i32x4 v;
    } pk;
#pragma unroll
    for (int e = 0; e < 8; ++e) {
      const int c = lq * 8 + e;
      float v = 0.f;
      if (c < C_ && tr < TIN - 1) v = xb[c * TIN + tr];
      pk.u[e] = f2bf(v);
    }
    *(i32x4*)(xt + (size_t)tr * 32 + q * 8) = pk.v;
  }
}

#define MFMA12(A, Bv)                                                          \
  do {                                                                         \
    _Pragma("unroll") for (int nt_ = 0; nt_ < 3; ++nt_) {                      \
      _Pragma("unroll") for (int m_ = 0; m_ < 4; ++m_) {                       \
        acc[m_][nt_] =                                                         \
            __builtin_amdgcn_mfma_f32_16x16x32_bf16(A[m_], Bv[nt_], acc[m_][nt_], 0, 0, 0); \
      }                                                                        \
    }                                                                          \
  } while (0)

#define LDA(J, A)                                                              \
  do {                                                                         \
    const int tl_ = tbl + (J);                                                 \
    const char* ap_ = sm + tl_ * 64 + ((lg ^ ((tl_ >> 1) & 3)) << 4);          \
    _Pragma("unroll") for (int m_ = 0; m_ < 4; ++m_) {                         \
      A[m_] = *(const bf16x8*)(ap_ + m_ * 1024);                               \
    }                                                                          \
  } while (0)

#define LDB(J, Bv)                                                             \
  do {                                                                         \
    const unsigned short* bp_ = WBs + (J) * 1536;                              \
    _Pragma("unroll") for (int nt_ = 0; nt_ < 3; ++nt_) {                      \
      Bv[nt_] = *(const bf16x8*)(bp_ + nt_ * 512);                             \
    }                                                                          \
  } while (0)

// 2048 blocks = (sample b, quarter p). 256 thr = 4 waves; wave wv owns output
// rows [p*256 + wv*64, +64). A staged via global_load_lds from pre-transposed
// XTg (zero staging VALU); B from global (L2-hot 48KB/sid), 3-slot ring
// prefetched 2 ahead ((j+2)%3 != j%3, no alias).
__global__ __launch_bounds__(256, 4) void conv_kernel(
    const unsigned short* __restrict__ XTg, const unsigned short* __restrict__ WBg,
    const float* __restrict__ x, const float* __restrict__ bias,
    float* __restrict__ pooled, float* __restrict__ part_sum,
    float* __restrict__ part_sq) {
  extern __shared__ __align__(16) char sm[];
  const int blk = blockIdx.x;
  const int b = blk >> 2;
  const int p = blk & 3;
  const int rbg = p * 256;  // global output-row base of this piece
  const int tid = threadIdx.x;

  int s = (int)rintf(x[(size_t)b * (C_ * TIN) + (TIN - 1)] * 1e-6f) - 1;
  s = __builtin_amdgcn_readfirstlane(min(max(s, 0), 8));

  // ---- stage 320 rows of XTg via async DMA (linear, swizzle pre-baked) ----
  {
    const char* src = (const char*)XTg + ((size_t)b * XTROWS + rbg) * 64;
#pragma unroll
    for (int r = 0; r < 5; ++r) {
      const int i = tid + r * 256;  // 1280 chunks of 16B
      gll16(src + i * 16, sm + i * 16);
    }
  }
  __syncthreads();  // drains vmcnt -> LDS image complete

  const int lane = tid & 63;
  const int wv = tid >> 6;
  const int l15 = lane & 15;
  const int lg = lane >> 4;
  const int tbl = wv * 64 + l15;  // local m=0 A-row for this lane

  const unsigned short* WBs = WBg + (size_t)s * WB_ELEM_S + (l15 * 32 + lg * 8);

  f32x4 acc[4][3];
#pragma unroll
  for (int m = 0; m < 4; ++m)
#pragma unroll
    for (int nt = 0; nt < 3; ++nt) acc[m][nt] = (f32x4){0.f, 0.f, 0.f, 0.f};

  bf16x8 Aa[2][4];
  bf16x8 Bb[3][3];

  LDA(0, Aa[0]);
  LDB(0, Bb[0]);
  LDB(1, Bb[1]);

#pragma unroll
  for (int j = 0; j <= 24; ++j) {
    if (j < 24) LDA(j + 1, Aa[(j + 1) & 1]);
    if (j + 2 <= 24) LDB(j + 2, Bb[(j + 2) % 3]);
    __builtin_amdgcn_s_setprio(1);
    MFMA12(Aa[j & 1], Bb[j % 3]);
    __builtin_amdgcn_s_setprio(0);
  }

  // ---- epilogue: bias + ELU, BN partials, pooled-window partials ----
  float bv[3];
#pragma unroll
  for (int nt = 0; nt < 3; ++nt) {
    const int k = nt * 16 + l15;
    bv[nt] = bias[s * K_ + (k < K_ ? k : 0)];
  }
  const int wbase = rbg / P_;  // 0,2,5,7
  const int base100 = wbase * P_;
  float sY[3] = {0.f, 0.f, 0.f}, sY2[3] = {0.f, 0.f, 0.f};
  float pw[4][3];
#pragma unroll
  for (int w4 = 0; w4 < 4; ++w4)
#pragma unroll
    for (int nt = 0; nt < 3; ++nt) pw[w4][nt] = 0.f;

#pragma unroll
  for (int m = 0; m < 4; ++m) {
#pragma unroll
    for (int i = 0; i < 4; ++i) {
      const int t = rbg + wv * 64 + m * 16 + lg * 4 + i;
      const bool valid = (t < TO);
      const bool pool = (t < NW * P_);
      const int d = t - base100;
#pragma unroll
      for (int nt = 0; nt < 3; ++nt) {
        const float v = acc[m][nt][i] + bv[nt];
        const float y = v > 0.f ? v : (__expf(v) - 1.f);
        if (valid) {
          sY[nt] += y;
          sY2[nt] = fmaf(y, y, sY2[nt]);
          if (pool) {
            if (d < P_)
              pw[0][nt] += y;
            else if (d < 2 * P_)
              pw[1][nt] += y;
            else if (d < 3 * P_)
              pw[2][nt] += y;
            else
              pw[3][nt] += y;
          }
        }
      }
    }
  }

  float* red = (float*)(sm + RED_OFF);
#pragma unroll
  for (int nt = 0; nt < 3; ++nt) {
#pragma unroll
    for (int r = 16; r <= 32; r <<= 1) {
      pw[0][nt] += __shfl_xor(pw[0][nt], r, 64);
      pw[1][nt] += __shfl_xor(pw[1][nt], r, 64);
      pw[2][nt] += __shfl_xor(pw[2][nt], r, 64);
      pw[3][nt] += __shfl_xor(pw[3][nt], r, 64);
      sY[nt] += __shfl_xor(sY[nt], r, 64);
      sY2[nt] += __shfl_xor(sY2[nt], r, 64);
    }
    const int k = nt * 16 + l15;
    if (lane < 16 && k < K_) {
      float* pb = pooled + (size_t)b * FCIN + k * NW;
#pragma unroll
      for (int w4 = 0; w4 < 4; ++w4) {
        const int wg = wbase + w4;
        if (wg <= NW - 1 && pw[w4][nt] != 0.f) atomicAdd(&pb[wg], pw[w4][nt]);
      }
      red[k * 4 + wv] = sY[nt];
      red[K_ * 4 + k * 4 + wv] = sY2[nt];
    }
  }
  __syncthreads();
  if (tid < K_) {
    float a = 0.f, q = 0.f;
#pragma unroll
    for (int i = 0; i < 4; ++i) {
      a += red[tid * 4 + i];
      q += red[K_ * 4 + tid * 4 + i];
    }
    part_sum[(size_t)tid * NBLKQ + blk] = a;
    part_sq[(size_t)tid * NBLKQ + blk] = q;
  }
}

__global__ __launch_bounds__(256) void stats_kernel(
    const float* __restrict__ part_sum, const float* __restrict__ part_sq,
    const float* __restrict__ gamma, const float* __restrict__ beta,
    float* __restrict__ ss) {
  const int k = blockIdx.x;
  float s = 0.f, q = 0.f;
  for (int i = threadIdx.x; i < NBLKQ; i += 256) {
    s += part_sum[(size_t)k * NBLKQ + i];
    q += part_sq[(size_t)k * NBLKQ + i];
  }
  s = waveReduceSum(s);
  q = waveReduceSum(q);
  __shared__ float ls[4], lq[4];
  const int wave = threadIdx.x >> 6, lane = threadIdx.x & 63;
  if (lane == 0) {
    ls[wave] = s;
    lq[wave] = q;
  }
  __syncthreads();
  if (threadIdx.x == 0) {
    const float S = ls[0] + ls[1] + ls[2] + ls[3];
    const float Q = lq[0] + lq[1] + lq[2] + lq[3];
    const float N = (float)B_ * (float)TO;
    const float mean = S / N;
    const float var = Q / N - mean * mean;
    const float sc = gamma[k] / sqrtf(var + 1e-5f);
    ss[k] = sc;
    ss[K_ + k] = beta[k] - mean * sc;
  }
}

__global__ __launch_bounds__(256) void fc_kernel(
    const float* __restrict__ pooled, const float* __restrict__ ss,
    const float* __restrict__ fc_w, const float* __restrict__ fc_b,
    float* __restrict__ out) {
  const int bb = blockIdx.x;
  const int n = threadIdx.x >> 6;
  const int lane = threadIdx.x & 63;
  float acc = 0.f;
  for (int i = lane; i < FCIN; i += 64) {
    const int k = i / NW;
    const float y = pooled[(size_t)bb * FCIN + i] * (1.f / (float)P_) * ss[k] + ss[K_ + k];
    acc = fmaf(y, fc_w[n * FCIN + i], acc);
  }
  acc = waveReduceSum(acc);
  if (lane == 0) out[bb * NOUT + n] = acc + fc_b[n];
}

extern "C" void kernel_launch(void* const* d_in, const int* in_sizes, int n_in,
                              void* d_out, int out_size, void* d_ws, size_t ws_size,
                              hipStream_t stream) {
  const float* x = (const float*)d_in[0];
  const float* W = (const float*)d_in[1];
  const float* bias = (const float*)d_in[2];
  const float* gamma = (const float*)d_in[3];
  const float* beta = (const float*)d_in[4];
  const float* fc_w = (const float*)d_in[5];
  const float* fc_b = (const float*)d_in[6];
  float* out = (float*)d_out;

  char* ws = (char*)d_ws;
  float* pooled = (float*)ws;                             // 737280 B
  float* part_sum = (float*)(ws + 737280);                // 40*2048*4 = 327680
  float* part_sq = (float*)(ws + 1064960);                // 327680
  unsigned short* WBg = (unsigned short*)(ws + 1392640);  // 691200
  float* ss = (float*)(ws + 2083840);                     // 320
  unsigned short* XTg = (unsigned short*)(ws + 2084160);  // 512*1088*64 = 35.65 MB

  (void)hipFuncSetAttribute((const void*)conv_kernel,
                            hipFuncAttributeMaxDynamicSharedMemorySize, LDS_TOTAL);

  (void)hipMemsetAsync(pooled, 0, 737280, stream);
  wconv_kernel<<<9 * KS_, 192, 0, stream>>>(W, WBg);
  xpose_kernel<<<B_, 256, 0, stream>>>(x, XTg);
  conv_kernel<<<NBLKQ, 256, LDS_TOTAL, stream>>>(XTg, WBg, x, bias, pooled,
                                                 part_sum, part_sq);
  stats_kernel<<<K_, 256, 0, stream>>>(part_sum, part_sq, gamma, beta, ss);
  fc_kernel<<<B_, 256, 0, stream>>>(pooled, ss, fc_w, fc_b, out);
}

// Round 10
// 100.281 us; speedup vs baseline: 1.2684x; 1.2684x over previous
//
#include <hip/hip_runtime.h>
#include <hip/hip_bf16.h>

#define B_ 512
#define C_ 22
#define TIN 1001
#define K_ 40
#define KS_ 25
#define TO 976
#define P_ 100
#define NW 9
#define NOUT 4
#define FCIN 360

#define XTROWS 1088               /* padded rows of XTg (0..999 data, rest 0) */
#define QR 272                    /* rows per xpose block (XTROWS/4) */
#define SROWS 320                 /* rows staged per conv block */
#define STG_BYTES (SROWS * 64)    /* 20480 */
#define RED_OFF STG_BYTES
#define RED_BYTES (K_ * 4 * 2 * 4) /* 1280 */
#define LDS_TOTAL (RED_OFF + RED_BYTES) /* 21760 */
#define NBLKQ 2048
#define NPAD 48
#define WB_ELEM_S (KS_ * NPAD * 32) /* 38400 */

typedef __attribute__((ext_vector_type(8))) short bf16x8;
typedef __attribute__((ext_vector_type(4))) float f32x4;
typedef __attribute__((ext_vector_type(4))) int i32x4;

__device__ __forceinline__ float waveReduceSum(float v) {
#pragma unroll
  for (int m = 32; m >= 1; m >>= 1) v += __shfl_xor(v, m, 64);
  return v;
}

__device__ __forceinline__ unsigned short f2bf(float f) {
  __hip_bfloat16 h = __float2bfloat16(f);
  return *reinterpret_cast<unsigned short*>(&h);
}

__device__ __forceinline__ void gll16(const void* g, void* l) {
  __builtin_amdgcn_global_load_lds(
      (const __attribute__((address_space(1))) unsigned int*)g,
      (__attribute__((address_space(3))) unsigned int*)l, 16, 0, 0);
}

// W[s][n][c][j] fp32 -> WBg[s][j][n(48)][c(32)] bf16, zero-padded.
__global__ __launch_bounds__(192) void wconv_kernel(const float* __restrict__ W,
                                                    unsigned short* __restrict__ WBg) {
  const int s = blockIdx.x / KS_;
  const int j = blockIdx.x % KS_;
  const int n = threadIdx.x >> 2;
  const int q = threadIdx.x & 3;
  union {
    unsigned short u[8];
    i32x4 v;
  } pk;
#pragma unroll
  for (int e = 0; e < 8; ++e) {
    const int c = q * 8 + e;
    float v = 0.f;
    if (n < K_ && c < C_) v = W[(((size_t)s * K_ + n) * C_ + c) * KS_ + j];
    pk.u[e] = f2bf(v);
  }
  *(i32x4*)(WBg + ((size_t)(s * KS_ + j) * NPAD + n) * 32 + q * 8) = pk.v;
}

// x[b][c][t] fp32 -> XTg[b][t(1088)][c(32)] bf16, chunk-XOR swizzle baked:
// physical chunk q at row t holds logical chunk q ^ ((t>>1)&3). Rows >= 1000
// are zeros. 2048 blocks = (b, quarter); task = tr*4+q so lane-consecutive
// writes are contiguous 16B chunks (coalesced store path).
__global__ __launch_bounds__(256) void xpose_kernel(const float* __restrict__ x,
                                                    unsigned short* __restrict__ XTg) {
  const int blk = blockIdx.x;
  const int b = blk >> 2;
  const int p = blk & 3;
  const float* xb = x + (size_t)b * (C_ * TIN);
  unsigned short* xt = XTg + ((size_t)b * XTROWS + p * QR) * 32;
#pragma unroll
  for (int r = 0; r < 5; ++r) {  // 4*272 = 1088 tasks
    const int task = threadIdx.x + r * 256;
    if (task < 4 * QR) {
      const int trl = task >> 2;  // local row
      const int q = task & 3;     // physical 16B chunk
      const int tr = p * QR + trl;
      const int lq = q ^ ((tr >> 1) & 3);
      union {
        unsigned short u[8];
        i32x4 v;
      } pk;
#pragma unroll
      for (int e = 0; e < 8; ++e) {
        const int c = lq * 8 + e;
        float v = 0.f;
        if (c < C_ && tr < TIN - 1) v = xb[c * TIN + tr];
        pk.u[e] = f2bf(v);
      }
      *(i32x4*)(xt + (size_t)trl * 32 + q * 8) = pk.v;
    }
  }
}

#define MFMA12(A, Bv)                                                          \
  do {                                                                         \
    _Pragma("unroll") for (int nt_ = 0; nt_ < 3; ++nt_) {                      \
      _Pragma("unroll") for (int m_ = 0; m_ < 4; ++m_) {                       \
        acc[m_][nt_] =                                                         \
            __builtin_amdgcn_mfma_f32_16x16x32_bf16(A[m_], Bv[nt_], acc[m_][nt_], 0, 0, 0); \
      }                                                                        \
    }                                                                          \
  } while (0)

#define LDA(J, A)                                                              \
  do {                                                                         \
    const int tl_ = tbl + (J);                                                 \
    const char* ap_ = sm + tl_ * 64 + ((lg ^ ((tl_ >> 1) & 3)) << 4);          \
    _Pragma("unroll") for (int m_ = 0; m_ < 4; ++m_) {                         \
      A[m_] = *(const bf16x8*)(ap_ + m_ * 1024);                               \
    }                                                                          \
  } while (0)

#define LDB(J, Bv)                                                             \
  do {                                                                         \
    const unsigned short* bp_ = WBs + (J) * 1536;                              \
    _Pragma("unroll") for (int nt_ = 0; nt_ < 3; ++nt_) {                      \
      Bv[nt_] = *(const bf16x8*)(bp_ + nt_ * 512);                             \
    }                                                                          \
  } while (0)

// 2048 blocks = (sample b, quarter p). 256 thr = 4 waves; wave wv owns output
// rows [p*256 + wv*64, +64). A staged via global_load_lds from pre-transposed
// XTg; in the k-loop A is a 3-ring (2-step lead > LDS latency) and B a 4-ring
// with 3-step lead (> L2 latency). No ring aliasing; no setprio (hurts
// barrier-free GEMM loops, m190).
__global__ __launch_bounds__(256, 3) void conv_kernel(
    const unsigned short* __restrict__ XTg, const unsigned short* __restrict__ WBg,
    const float* __restrict__ x, const float* __restrict__ bias,
    float* __restrict__ pooled, float* __restrict__ part_sum,
    float* __restrict__ part_sq) {
  extern __shared__ __align__(16) char sm[];
  const int blk = blockIdx.x;
  const int b = blk >> 2;
  const int p = blk & 3;
  const int rbg = p * 256;  // global output-row base of this piece
  const int tid = threadIdx.x;

  int s = (int)rintf(x[(size_t)b * (C_ * TIN) + (TIN - 1)] * 1e-6f) - 1;
  s = __builtin_amdgcn_readfirstlane(min(max(s, 0), 8));

  // ---- stage 320 rows of XTg via async DMA (linear, swizzle pre-baked) ----
  {
    const char* src = (const char*)XTg + ((size_t)b * XTROWS + rbg) * 64;
#pragma unroll
    for (int r = 0; r < 5; ++r) {
      const int i = tid + r * 256;  // 1280 chunks of 16B
      gll16(src + i * 16, sm + i * 16);
    }
  }
  __syncthreads();  // drains vmcnt -> LDS image complete

  const int lane = tid & 63;
  const int wv = tid >> 6;
  const int l15 = lane & 15;
  const int lg = lane >> 4;
  const int tbl = wv * 64 + l15;  // local m=0 A-row for this lane

  const unsigned short* WBs = WBg + (size_t)s * WB_ELEM_S + (l15 * 32 + lg * 8);

  f32x4 acc[4][3];
#pragma unroll
  for (int m = 0; m < 4; ++m)
#pragma unroll
    for (int nt = 0; nt < 3; ++nt) acc[m][nt] = (f32x4){0.f, 0.f, 0.f, 0.f};

  bf16x8 Aa[3][4];
  bf16x8 Bb[4][3];

  LDA(0, Aa[0]);
  LDA(1, Aa[1]);
  LDB(0, Bb[0]);
  LDB(1, Bb[1]);
  LDB(2, Bb[2]);

#pragma unroll
  for (int j = 0; j <= 24; ++j) {
    if (j + 2 <= 24) LDA(j + 2, Aa[(j + 2) % 3]);
    if (j + 3 <= 24) LDB(j + 3, Bb[(j + 3) & 3]);
    MFMA12(Aa[j % 3], Bb[j & 3]);
  }

  // ---- epilogue: bias + ELU, BN partials, pooled-window partials ----
  float bv[3];
#pragma unroll
  for (int nt = 0; nt < 3; ++nt) {
    const int k = nt * 16 + l15;
    bv[nt] = bias[s * K_ + (k < K_ ? k : 0)];
  }
  const int wbase = rbg / P_;  // 0,2,5,7
  const int base100 = wbase * P_;
  float sY[3] = {0.f, 0.f, 0.f}, sY2[3] = {0.f, 0.f, 0.f};
  float pw[4][3];
#pragma unroll
  for (int w4 = 0; w4 < 4; ++w4)
#pragma unroll
    for (int nt = 0; nt < 3; ++nt) pw[w4][nt] = 0.f;

#pragma unroll
  for (int m = 0; m < 4; ++m) {
#pragma unroll
    for (int i = 0; i < 4; ++i) {
      const int t = rbg + wv * 64 + m * 16 + lg * 4 + i;
      const bool valid = (t < TO);
      const bool pool = (t < NW * P_);
      const int d = t - base100;
#pragma unroll
      for (int nt = 0; nt < 3; ++nt) {
        const float v = acc[m][nt][i] + bv[nt];
        const float y = v > 0.f ? v : (__expf(v) - 1.f);
        if (valid) {
          sY[nt] += y;
          sY2[nt] = fmaf(y, y, sY2[nt]);
          if (pool) {
            if (d < P_)
              pw[0][nt] += y;
            else if (d < 2 * P_)
              pw[1][nt] += y;
            else if (d < 3 * P_)
              pw[2][nt] += y;
            else
              pw[3][nt] += y;
          }
        }
      }
    }
  }

  float* red = (float*)(sm + RED_OFF);
#pragma unroll
  for (int nt = 0; nt < 3; ++nt) {
#pragma unroll
    for (int r = 16; r <= 32; r <<= 1) {
      pw[0][nt] += __shfl_xor(pw[0][nt], r, 64);
      pw[1][nt] += __shfl_xor(pw[1][nt], r, 64);
      pw[2][nt] += __shfl_xor(pw[2][nt], r, 64);
      pw[3][nt] += __shfl_xor(pw[3][nt], r, 64);
      sY[nt] += __shfl_xor(sY[nt], r, 64);
      sY2[nt] += __shfl_xor(sY2[nt], r, 64);
    }
    const int k = nt * 16 + l15;
    if (lane < 16 && k < K_) {
      float* pb = pooled + (size_t)b * FCIN + k * NW;
#pragma unroll
      for (int w4 = 0; w4 < 4; ++w4) {
        const int wg = wbase + w4;
        if (wg <= NW - 1 && pw[w4][nt] != 0.f) atomicAdd(&pb[wg], pw[w4][nt]);
      }
      red[k * 4 + wv] = sY[nt];
      red[K_ * 4 + k * 4 + wv] = sY2[nt];
    }
  }
  __syncthreads();
  if (tid < K_) {
    float a = 0.f, q = 0.f;
#pragma unroll
    for (int i = 0; i < 4; ++i) {
      a += red[tid * 4 + i];
      q += red[K_ * 4 + tid * 4 + i];
    }
    part_sum[(size_t)tid * NBLKQ + blk] = a;
    part_sq[(size_t)tid * NBLKQ + blk] = q;
  }
}

__global__ __launch_bounds__(256) void stats_kernel(
    const float* __restrict__ part_sum, const float* __restrict__ part_sq,
    const float* __restrict__ gamma, const float* __restrict__ beta,
    float* __restrict__ ss) {
  const int k = blockIdx.x;
  float s = 0.f, q = 0.f;
  for (int i = threadIdx.x; i < NBLKQ; i += 256) {
    s += part_sum[(size_t)k * NBLKQ + i];
    q += part_sq[(size_t)k * NBLKQ + i];
  }
  s = waveReduceSum(s);
  q = waveReduceSum(q);
  __shared__ float ls[4], lq[4];
  const int wave = threadIdx.x >> 6, lane = threadIdx.x & 63;
  if (lane == 0) {
    ls[wave] = s;
    lq[wave] = q;
  }
  __syncthreads();
  if (threadIdx.x == 0) {
    const float S = ls[0] + ls[1] + ls[2] + ls[3];
    const float Q = lq[0] + lq[1] + lq[2] + lq[3];
    const float N = (float)B_ * (float)TO;
    const float mean = S / N;
    const float var = Q / N - mean * mean;
    const float sc = gamma[k] / sqrtf(var + 1e-5f);
    ss[k] = sc;
    ss[K_ + k] = beta[k] - mean * sc;
  }
}

__global__ __launch_bounds__(256) void fc_kernel(
    const float* __restrict__ pooled, const float* __restrict__ ss,
    const float* __restrict__ fc_w, const float* __restrict__ fc_b,
    float* __restrict__ out) {
  const int bb = blockIdx.x;
  const int n = threadIdx.x >> 6;
  const int lane = threadIdx.x & 63;
  float acc = 0.f;
  for (int i = lane; i < FCIN; i += 64) {
    const int k = i / NW;
    const float y = pooled[(size_t)bb * FCIN + i] * (1.f / (float)P_) * ss[k] + ss[K_ + k];
    acc = fmaf(y, fc_w[n * FCIN + i], acc);
  }
  acc = waveReduceSum(acc);
  if (lane == 0) out[bb * NOUT + n] = acc + fc_b[n];
}

extern "C" void kernel_launch(void* const* d_in, const int* in_sizes, int n_in,
                              void* d_out, int out_size, void* d_ws, size_t ws_size,
                              hipStream_t stream) {
  const float* x = (const float*)d_in[0];
  const float* W = (const float*)d_in[1];
  const float* bias = (const float*)d_in[2];
  const float* gamma = (const float*)d_in[3];
  const float* beta = (const float*)d_in[4];
  const float* fc_w = (const float*)d_in[5];
  const float* fc_b = (const float*)d_in[6];
  float* out = (float*)d_out;

  char* ws = (char*)d_ws;
  float* pooled = (float*)ws;                             // 737280 B
  float* part_sum = (float*)(ws + 737280);                // 40*2048*4 = 327680
  float* part_sq = (float*)(ws + 1064960);                // 327680
  unsigned short* WBg = (unsigned short*)(ws + 1392640);  // 691200
  float* ss = (float*)(ws + 2083840);                     // 320
  unsigned short* XTg = (unsigned short*)(ws + 2084160);  // 512*1088*64 = 35.65 MB

  (void)hipFuncSetAttribute((const void*)conv_kernel,
                            hipFuncAttributeMaxDynamicSharedMemorySize, LDS_TOTAL);

  (void)hipMemsetAsync(pooled, 0, 737280, stream);
  wconv_kernel<<<9 * KS_, 192, 0, stream>>>(W, WBg);
  xpose_kernel<<<NBLKQ, 256, 0, stream>>>(x, XTg);
  conv_kernel<<<NBLKQ, 256, LDS_TOTAL, stream>>>(XTg, WBg, x, bias, pooled,
                                                 part_sum, part_sq);
  stats_kernel<<<K_, 256, 0, stream>>>(part_sum, part_sq, gamma, beta, ss);
  fc_kernel<<<B_, 256, 0, stream>>>(pooled, ss, fc_w, fc_b, out);
}